// Round 3
// baseline (341.659 us; speedup 1.0000x reference)
//
#include <hip/hip_runtime.h>
#include <stdint.h>

// B=512, T=256, N_EMBED=384, HEAD_SIZE=64
// Round-3: SPLIT the fused kernel. Diagnosis: fused 160KiB-LDS block => 1
// block/CU, 16-wave barriers + causal wave imbalance => latency-bound at
// ~114us (5x the pipe model). Split restores TLP (4-5 blocks/CU each).
//   prep_w: W fp32 -> bf16 fragment-ordered Wt3 (ws, unchanged).
//   proj:   QKV GEMM. 256 thr, wave = one 16-row m-tile, full N=192.
//           x direct-to-reg A-frags (no x staging), W via 24KB dbuf LDS
//           (1 barrier/kc), epilogue LDS-bounce -> coalesced ws stores.
//   attn:   causal flash attention, wave = one q-tile, K/Q/V fragments read
//           straight from ws (coalesced 16B/lane, L2/LLC-hot), P via LDS.
// Numerics bit-identical to the fused version (same f2bf, same MFMA order).
// ws layout: Wt3 @ 0 (147456 B); KQV @ 1 MiB: per batch 49152 shorts
//            (Kf 16384 | Qf 16384 | Vf 16384), same frag layouts as before.

typedef short s16x8 __attribute__((ext_vector_type(8)));
typedef float f32x4 __attribute__((ext_vector_type(4)));

#define LOG2E_OVER_8 0.18033688011112042f

__device__ inline short f2bf(float f) {
  union { float f; uint32_t u; } v; v.f = f;
  uint32_t r = (v.u + 0x7fffu + ((v.u >> 16) & 1u)) >> 16;  // RNE
  return (short)r;
}

// ---- Kernel 0: W fp32 -> bf16 fragment-ordered Wt3, fold 0.125*log2e into Wq
__global__ __launch_bounds__(256) void prep_w(const float* __restrict__ Wk,
                                              const float* __restrict__ Wq,
                                              const float* __restrict__ Wv,
                                              short* __restrict__ Wt3) {
  int idx = blockIdx.x * 256 + threadIdx.x;  // 0..73727
  int j = idx & 7;
  int lane = (idx >> 3) & 63;
  int rest = idx >> 9;          // 0..143
  int ntile = rest % 12;
  int kc = rest / 12;
  int n = ntile * 16 + (lane & 15);
  int kk = (lane >> 4) * 8 + j;
  int col = n & 63;
  int w = n >> 6;
  const float* W = (w == 0) ? Wk : (w == 1) ? Wq : Wv;
  float v = W[(kc * 32 + kk) * 64 + col];
  if (w == 1) v *= LOG2E_OVER_8;
  Wt3[idx] = f2bf(v);
}

// ---- Kernel 1: QKV projection. grid 2048, block 256 (4 waves).
// Block = 64 rows (4 m-tiles) of one batch, full N=192. Wave owns 1 m-tile.
__global__ __launch_bounds__(256, 4) void proj(const float* __restrict__ x,
                                               const short* __restrict__ Wt3,
                                               short* __restrict__ kqv) {
  __shared__ __align__(16) short Wl[12288];  // 24KB: W dbuf; epilogue C bounce

  const int tid = threadIdx.x;
  const int wave = tid >> 6;
  const int lane = tid & 63;
  const int l15 = lane & 15;
  const int quad = lane >> 4;
  const int blk = blockIdx.x;
  const int b = blk >> 2;          // batch
  const int tb = (blk & 3) * 4;    // first 16-row tile of this block in batch
  const int t = tb + wave;         // wave's tile 0..15

  // x A-frag source: lane reads row (t*16+l15), cols quad*8..+7 (+kc*32)
  const float* xw = x + (long)b * (256 * 384) + (t * 16 + l15) * 384 + quad * 8;
  const int so = tid * 8;  // W stage slot (shorts)

  f32x4 acc[12];
#pragma unroll
  for (int nt = 0; nt < 12; ++nt) acc[nt] = (f32x4)0.0f;

  // prologue: kc=0 operands
  f32x4 xa0 = *(const f32x4*)(xw);
  f32x4 xa1 = *(const f32x4*)(xw + 4);
  s16x8 w0 = *(const s16x8*)(Wt3 + so);
  s16x8 w1 = *(const s16x8*)(Wt3 + so + 2048);
  s16x8 w2 = *(const s16x8*)(Wt3 + so + 4096);

#pragma unroll
  for (int kc = 0; kc < 12; ++kc) {
    short* buf = Wl + (kc & 1) * 6144;
    *(s16x8*)(buf + so) = w0;
    *(s16x8*)(buf + so + 2048) = w1;
    *(s16x8*)(buf + so + 4096) = w2;

    s16x8 af;
    af[0] = f2bf(xa0[0]); af[1] = f2bf(xa0[1]); af[2] = f2bf(xa0[2]); af[3] = f2bf(xa0[3]);
    af[4] = f2bf(xa1[0]); af[5] = f2bf(xa1[1]); af[6] = f2bf(xa1[2]); af[7] = f2bf(xa1[3]);

    __syncthreads();  // stage visible; prior-parity reads (kc-2) long done

    if (kc < 11) {  // prefetch next kc (in flight across the MFMA cluster)
      xa0 = *(const f32x4*)(xw + (kc + 1) * 32);
      xa1 = *(const f32x4*)(xw + (kc + 1) * 32 + 4);
      w0 = *(const s16x8*)(Wt3 + (kc + 1) * 6144 + so);
      w1 = *(const s16x8*)(Wt3 + (kc + 1) * 6144 + so + 2048);
      w2 = *(const s16x8*)(Wt3 + (kc + 1) * 6144 + so + 4096);
    }

#pragma unroll
    for (int nt = 0; nt < 12; ++nt) {
      s16x8 bfv = *(const s16x8*)(buf + nt * 512 + lane * 8);
      acc[nt] = __builtin_amdgcn_mfma_f32_16x16x32_bf16(af, bfv, acc[nt], 0, 0, 0);
    }
  }
  __syncthreads();  // Wl free for epilogue bounce

  // epilogue: C frags -> LDS (K @0, Q @4096, V @8192; each 4096 shorts),
  // then coalesced 16B copies to ws. base_sub = tb*1024 localizes the slot.
  const int base_sub = tb * 1024;
#pragma unroll
  for (int nt = 0; nt < 12; ++nt) {
    const int h = (nt * 16 + l15) & 63;
    const int which = nt >> 2;
#pragma unroll
    for (int r = 0; r < 4; ++r) {
      const short v = f2bf(acc[nt][r]);
      const int row = t * 16 + quad * 4 + r;
      if (which == 2) {
        const int idx = ((row >> 5) * 4 + (h >> 4)) * 512 +
                        ((h & 15) + ((row & 31) >> 3) * 16) * 8 + (row & 7) - base_sub;
        Wl[8192 + idx] = v;
      } else {
        const int idx = ((row >> 4) * 2 + (h >> 5)) * 512 +
                        ((row & 15) + ((h & 31) >> 3) * 16) * 8 + (h & 7) - base_sub;
        Wl[which * 4096 + idx] = v;
      }
    }
  }
  __syncthreads();  // V slots interleave rows across waves

  short* dstK = kqv + (long)b * 49152 + base_sub;
  short* dstQ = dstK + 16384;
  short* dstV = dstK + 32768;
  *(s16x8*)(dstK + so)        = *(const s16x8*)(Wl + so);
  *(s16x8*)(dstK + 2048 + so) = *(const s16x8*)(Wl + 2048 + so);
  *(s16x8*)(dstQ + so)        = *(const s16x8*)(Wl + 4096 + so);
  *(s16x8*)(dstQ + 2048 + so) = *(const s16x8*)(Wl + 6144 + so);
  *(s16x8*)(dstV + so)        = *(const s16x8*)(Wl + 8192 + so);
  *(s16x8*)(dstV + 2048 + so) = *(const s16x8*)(Wl + 10240 + so);
}

// ---- Kernel 2: causal flash attention. grid 2048, block 256 (4 waves).
// Wave = one 16-row q-tile; K/Q/V fragments read directly from ws.
__global__ __launch_bounds__(256, 4) void attn(const short* __restrict__ kqv,
                                               float* __restrict__ out) {
  __shared__ __align__(16) short P[8192];  // 4 waves x 2048 shorts (A-frag)

  const int tid = threadIdx.x;
  const int wave = tid >> 6;
  const int lane = tid & 63;
  const int l15 = lane & 15;
  const int quad = lane >> 4;
  const int blk = blockIdx.x;
  const int b = blk >> 2;
  const int t = (blk & 3) * 4 + wave;  // q-tile 0..15
  const int q0 = t * 16;

  const short* Kg = kqv + (long)b * 49152;
  const short* Qg = Kg + 16384;
  const short* Vg = Kg + 32768;
  short* Pw = P + wave * 2048;

  s16x8 qf0 = *(const s16x8*)(Qg + (t * 2 + 0) * 512 + lane * 8);
  s16x8 qf1 = *(const s16x8*)(Qg + (t * 2 + 1) * 512 + lane * 8);

  f32x4 Oacc[4];
#pragma unroll
  for (int n = 0; n < 4; ++n) Oacc[n] = (f32x4)0.0f;
  float mrow[4] = {-1e30f, -1e30f, -1e30f, -1e30f};
  float lrow[4] = {0.f, 0.f, 0.f, 0.f};

  const int nb = (t >= 8) ? 2 : 1;
  for (int cb = 0; cb < nb; ++cb) {
    const int st0 = cb * 8;
    const bool last = (cb == nb - 1);
    const int nuse = last ? (t - cb * 8 + 1) : 8;

    float S[8][4];
#pragma unroll
    for (int n = 0; n < 8; ++n) {
      if (n < nuse) {
        s16x8 kf0 = *(const s16x8*)(Kg + ((st0 + n) * 2 + 0) * 512 + lane * 8);
        s16x8 kf1 = *(const s16x8*)(Kg + ((st0 + n) * 2 + 1) * 512 + lane * 8);
        f32x4 z = (f32x4)0.0f;
        z = __builtin_amdgcn_mfma_f32_16x16x32_bf16(qf0, kf0, z, 0, 0, 0);
        z = __builtin_amdgcn_mfma_f32_16x16x32_bf16(qf1, kf1, z, 0, 0, 0);
        if (last) {
          const int s_abs = cb * 128 + n * 16 + l15;
#pragma unroll
          for (int r = 0; r < 4; ++r) {
            const int q_abs = q0 + quad * 4 + r;
            S[n][r] = (s_abs > q_abs) ? -1e30f : z[r];
          }
        } else {
#pragma unroll
          for (int r = 0; r < 4; ++r) S[n][r] = z[r];
        }
      } else {
#pragma unroll
        for (int r = 0; r < 4; ++r) S[n][r] = -1e30f;
      }
    }

    // online softmax (base-2); row r lives in the 16 lanes of this quad
    float alpha[4];
#pragma unroll
    for (int r = 0; r < 4; ++r) {
      float mx = S[0][r];
#pragma unroll
      for (int n = 1; n < 8; ++n) mx = fmaxf(mx, S[n][r]);
      mx = fmaxf(mx, __shfl_xor(mx, 1));
      mx = fmaxf(mx, __shfl_xor(mx, 2));
      mx = fmaxf(mx, __shfl_xor(mx, 4));
      mx = fmaxf(mx, __shfl_xor(mx, 8));
      float mnew = fmaxf(mrow[r], mx);
      alpha[r] = __builtin_amdgcn_exp2f(mrow[r] - mnew);
      mrow[r] = mnew;
    }
    float rs[4] = {0.f, 0.f, 0.f, 0.f};
#pragma unroll
    for (int n = 0; n < 8; ++n) {
#pragma unroll
      for (int r = 0; r < 4; ++r) {
        float p = __builtin_amdgcn_exp2f(S[n][r] - mrow[r]);  // masked -> 0
        rs[r] += p;
        Pw[(n >> 1) * 512 + ((quad * 4 + r) + ((n & 1) * 2 + (l15 >> 3)) * 16) * 8 + (l15 & 7)] = f2bf(p);
      }
    }
#pragma unroll
    for (int r = 0; r < 4; ++r) {
      float s = rs[r];
      s += __shfl_xor(s, 1);
      s += __shfl_xor(s, 2);
      s += __shfl_xor(s, 4);
      s += __shfl_xor(s, 8);
      lrow[r] = lrow[r] * alpha[r] + s;
#pragma unroll
      for (int n = 0; n < 4; ++n) Oacc[n][r] *= alpha[r];
    }
    // P strip is wave-private: drain DS writes before re-reading (no barrier)
    asm volatile("s_waitcnt lgkmcnt(0)" ::: "memory");

    // O += P V over the live 32-s blocks
    const int kblks = (nuse + 1) >> 1;
    for (int sb = 0; sb < kblks; ++sb) {
      s16x8 pf = *(const s16x8*)(Pw + sb * 512 + lane * 8);
#pragma unroll
      for (int n2 = 0; n2 < 4; ++n2) {
        s16x8 vfv = *(const s16x8*)(Vg + ((cb * 4 + sb) * 4 + n2) * 512 + lane * 8);
        Oacc[n2] = __builtin_amdgcn_mfma_f32_16x16x32_bf16(pf, vfv, Oacc[n2], 0, 0, 0);
      }
    }
  }

  float inv[4];
#pragma unroll
  for (int r = 0; r < 4; ++r) inv[r] = 1.0f / lrow[r];
  float* ob = out + ((long)b * 256 + q0 + quad * 4) * 64;
#pragma unroll
  for (int n = 0; n < 4; ++n)
#pragma unroll
    for (int r = 0; r < 4; ++r)
      ob[r * 64 + n * 16 + l15] = Oacc[n][r] * inv[r];
}

extern "C" void kernel_launch(void* const* d_in, const int* in_sizes, int n_in,
                              void* d_out, int out_size, void* d_ws, size_t ws_size,
                              hipStream_t stream) {
  const float* x = (const float*)d_in[0];
  const float* Wk = (const float*)d_in[1];
  const float* Wq = (const float*)d_in[2];
  const float* Wv = (const float*)d_in[3];
  float* out = (float*)d_out;
  short* Wt3 = (short*)d_ws;                        // 147456 B @ ws+0
  short* kqv = (short*)d_ws + (1 << 20) / 2;        // 50.3 MB @ ws+1MiB

  prep_w<<<288, 256, 0, stream>>>(Wk, Wq, Wv, Wt3);
  proj<<<2048, 256, 0, stream>>>(x, Wt3, kqv);
  attn<<<2048, 256, 0, stream>>>(kqv, out);
}

// Round 4
// 320.302 us; speedup vs baseline: 1.0667x; 1.0667x over previous
//
#include <hip/hip_runtime.h>
#include <stdint.h>

// B=512, T=256, N_EMBED=384, HEAD_SIZE=64
// One block per batch, 1024 threads (16 waves, 4/SIMD).
// Round-4 change vs round 2 (317.6us, fused_head ~114us):
//   Phase-1 kc loop: __syncthreads() -> {s_waitcnt lgkmcnt(0); raw s_barrier;
//   sched_barrier(0)}. HIP's __syncthreads lowers to a FULL vmcnt(0) drain
//   before s_barrier (m97), which serialized every kc on the freshly-issued
//   x/W prefetch loads (~900cyc HBM latency exposed 12x per block) and is why
//   R2's dbuf+2-deep prefetch gained exactly 0 vs R0. Raw barrier + lgkm-only
//   wait keeps reg-destined prefetches in flight across barriers (T4 pattern,
//   m201/m218). Dbuf parity argument for one-barrier-per-kc is unchanged.
// Everything else (phase 2, epilogue, numerics) byte-identical to round 2.
// LDS total = 163840 B: Kf 32K + Qf 32K + Vf 32K + P 64K
//             (P region aliases phase-1 staging dbuf: 2 x (Xc 16K + Wsl 12K)).

typedef short s16x8 __attribute__((ext_vector_type(8)));
typedef short s16x4 __attribute__((ext_vector_type(4)));
typedef float f32x4 __attribute__((ext_vector_type(4)));

#define LOG2E_OVER_8 0.18033688011112042f

__device__ inline short f2bf(float f) {
  union { float f; uint32_t u; } v; v.f = f;
  uint32_t r = (v.u + 0x7fffu + ((v.u >> 16) & 1u)) >> 16;  // RNE
  return (short)r;
}

// ---- Kernel 0: W fp32 -> bf16 fragment-ordered Wt3, fold 0.125*log2e into Wq
__global__ __launch_bounds__(256) void prep_w(const float* __restrict__ Wk,
                                              const float* __restrict__ Wq,
                                              const float* __restrict__ Wv,
                                              short* __restrict__ Wt3) {
  int idx = blockIdx.x * 256 + threadIdx.x;  // 0..73727
  int j = idx & 7;
  int lane = (idx >> 3) & 63;
  int rest = idx >> 9;          // 0..143
  int ntile = rest % 12;
  int kc = rest / 12;
  int n = ntile * 16 + (lane & 15);
  int kk = (lane >> 4) * 8 + j;
  int col = n & 63;
  int w = n >> 6;
  const float* W = (w == 0) ? Wk : (w == 1) ? Wq : Wv;
  float v = W[(kc * 32 + kk) * 64 + col];
  if (w == 1) v *= LOG2E_OVER_8;
  Wt3[idx] = f2bf(v);
}

// ---- Fused kernel: one block per batch, 1024 threads.
__global__ __launch_bounds__(1024, 4) void fused_head(const float* __restrict__ x,
                                                      const short* __restrict__ Wt3,
                                                      float* __restrict__ out) {
  __shared__ __align__(16) short LDS[81920];  // 163840 B
  short* Kf = LDS;            // [stile16*2+frag][lane*8+j]  (B-frag: n=s, k=h)
  short* Qf = LDS + 16384;    // [qtile16*2+frag][lane*8+j]  (A-frag: m=q, k=h)
  short* Vf = LDS + 32768;    // [sblk32*4+htile][lane*8+j]  (B-frag: n=h, k=s)
  short* Pb = LDS + 49152;    // phase 2: 16 waves x 2048 shorts (A-frag)
                              // phase 1 alias: staging dbuf, stride 14336 shorts

  const int tid = threadIdx.x;
  const int wave = tid >> 6;
  const int lane = tid & 63;
  const int l15 = lane & 15;
  const int quad = lane >> 4;
  const int b = blockIdx.x;
  const float* xb = x + (long)b * (256 * 384);

  // ======== Phase 1: QKV projection (kc-outer, dbuf staging) ========
  const int mgrp = wave >> 2;  // 4 m-tiles (64 rows)
  const int ngrp = wave & 3;   // 3 n-tiles (48 cols)

  // x staging: slot = tid + j*1024; m=slot>>3, kq=(slot&7)*4
  const int m0s = tid >> 3;
  const int kq0 = (tid & 7) * 4;
  const int xoff0 = m0s * 384 + kq0;
  const int xoff1 = xoff0 + 128 * 384;
  const int lds0 = (m0s >> 4) * 512 + ((m0s & 15) + (kq0 >> 3) * 16) * 8 + (kq0 & 7);
  const int lds1 = lds0 + 8 * 512;
  const bool wact = (tid < 768);

  f32x4 acc[4][3];
#pragma unroll
  for (int i = 0; i < 4; ++i)
#pragma unroll
    for (int k2 = 0; k2 < 3; ++k2) acc[i][k2] = (f32x4)0.0f;

  // 2-deep x prefetch: A holds even kc, B holds odd kc. W is 1-deep (L2-hot).
  f32x4 xA0 = *(const f32x4*)(xb + xoff0);
  f32x4 xA1 = *(const f32x4*)(xb + xoff1);
  f32x4 xB0 = *(const f32x4*)(xb + xoff0 + 32);
  f32x4 xB1 = *(const f32x4*)(xb + xoff1 + 32);
  s16x8 wv;
  if (wact) wv = *(const s16x8*)(Wt3 + tid * 8);

#pragma unroll
  for (int kc = 0; kc < 12; ++kc) {
    short* XcS = LDS + 49152 + (kc & 1) * 14336;  // staging x slice (8192 shorts)
    short* WslS = XcS + 8192;                     // staging W slice (6144 shorts)

    // stage current kc (convert to bf16). (kc&1) is compile-time (full unroll).
    {
      const f32x4 cx0 = (kc & 1) ? xB0 : xA0;
      const f32x4 cx1 = (kc & 1) ? xB1 : xA1;
      s16x4 h0, h1;
      h0[0] = f2bf(cx0[0]); h0[1] = f2bf(cx0[1]); h0[2] = f2bf(cx0[2]); h0[3] = f2bf(cx0[3]);
      h1[0] = f2bf(cx1[0]); h1[1] = f2bf(cx1[1]); h1[2] = f2bf(cx1[2]); h1[3] = f2bf(cx1[3]);
      *(s16x4*)(XcS + lds0) = h0;
      *(s16x4*)(XcS + lds1) = h1;
    }
    if (wact) *(s16x8*)(WslS + tid * 8) = wv;

    // ONE barrier per kc, WITHOUT the __syncthreads vmcnt(0) drain:
    // my ds_writes must be visible (lgkmcnt), reg-destined global prefetches
    // stay in flight. sched_barrier stops ds_reads hoisting above the barrier.
    asm volatile("s_waitcnt lgkmcnt(0)" ::: "memory");
    __builtin_amdgcn_s_barrier();
    __builtin_amdgcn_sched_barrier(0);

    // prefetch x for kc+2 into the just-consumed parity regs, W for kc+1.
    // These now genuinely survive the next barrier(s) in flight.
    if (kc + 2 < 12) {
      if (kc & 1) {
        xB0 = *(const f32x4*)(xb + xoff0 + (kc + 2) * 32);
        xB1 = *(const f32x4*)(xb + xoff1 + (kc + 2) * 32);
      } else {
        xA0 = *(const f32x4*)(xb + xoff0 + (kc + 2) * 32);
        xA1 = *(const f32x4*)(xb + xoff1 + (kc + 2) * 32);
      }
    }
    if (wact && (kc + 1 < 12))
      wv = *(const s16x8*)(Wt3 + (kc + 1) * 6144 + tid * 8);

    s16x8 af[4];
#pragma unroll
    for (int i = 0; i < 4; ++i)
      af[i] = *(const s16x8*)(XcS + (mgrp * 4 + i) * 512 + lane * 8);
#pragma unroll
    for (int k2 = 0; k2 < 3; ++k2) {
      s16x8 bfv = *(const s16x8*)(WslS + (ngrp * 3 + k2) * 512 + lane * 8);
#pragma unroll
      for (int i = 0; i < 4; ++i)
        acc[i][k2] = __builtin_amdgcn_mfma_f32_16x16x32_bf16(af[i], bfv, acc[i][k2], 0, 0, 0);
    }
  }

  // epilogue: C layout (row=quad*4+r, col=nt*16+l15) -> fragment-ordered K/Q/V
#pragma unroll
  for (int i = 0; i < 4; ++i) {
    const int rowb = (mgrp * 4 + i) * 16 + quad * 4;
#pragma unroll
    for (int k2 = 0; k2 < 3; ++k2) {
      const int nt = ngrp * 3 + k2;  // 0..11 (wave-uniform)
      const int h = (nt * 16 + l15) & 63;
      const int which = nt >> 2;
#pragma unroll
      for (int r = 0; r < 4; ++r) {
        const short v = f2bf(acc[i][k2][r]);
        const int row = rowb + r;
        if (which == 0)
          Kf[((row >> 4) * 2 + (h >> 5)) * 512 + ((row & 15) + ((h & 31) >> 3) * 16) * 8 + (h & 7)] = v;
        else if (which == 1)
          Qf[((row >> 4) * 2 + (h >> 5)) * 512 + ((row & 15) + ((h & 31) >> 3) * 16) * 8 + (h & 7)] = v;
        else
          Vf[((row >> 5) * 4 + (h >> 4)) * 512 + ((h & 15) + ((row & 31) >> 3) * 16) * 8 + (row & 7)] = v;
      }
    }
  }
  __syncthreads();  // K/Q/V complete; staging area (P region) free

  // ======== Phase 2: causal attention, wave w owns q-subtile w ========
  const int t = wave;
  const int q0 = t * 16;
  short* Pw = Pb + wave * 2048;

  s16x8 qf0 = *(const s16x8*)(Qf + (t * 2 + 0) * 512 + lane * 8);
  s16x8 qf1 = *(const s16x8*)(Qf + (t * 2 + 1) * 512 + lane * 8);

  f32x4 Oacc[4];
#pragma unroll
  for (int n = 0; n < 4; ++n) Oacc[n] = (f32x4)0.0f;
  float mrow[4] = {-1e30f, -1e30f, -1e30f, -1e30f};
  float lrow[4] = {0.f, 0.f, 0.f, 0.f};

  const int nb = (t >= 8) ? 2 : 1;
  for (int cb = 0; cb < nb; ++cb) {
    const int st0 = cb * 8;                       // first 16-s-tile of this 128-chunk
    const bool last = (cb == nb - 1);
    const int nuse = last ? (t - cb * 8 + 1) : 8; // tiles with any unmasked col

    float S[8][4];
#pragma unroll
    for (int n = 0; n < 8; ++n) {
      if (n < nuse) {
        s16x8 kf0 = *(const s16x8*)(Kf + ((st0 + n) * 2 + 0) * 512 + lane * 8);
        s16x8 kf1 = *(const s16x8*)(Kf + ((st0 + n) * 2 + 1) * 512 + lane * 8);
        f32x4 z = (f32x4)0.0f;
        z = __builtin_amdgcn_mfma_f32_16x16x32_bf16(qf0, kf0, z, 0, 0, 0);
        z = __builtin_amdgcn_mfma_f32_16x16x32_bf16(qf1, kf1, z, 0, 0, 0);
        if (last) {
          const int s_abs = cb * 128 + n * 16 + l15;
#pragma unroll
          for (int r = 0; r < 4; ++r) {
            const int q_abs = q0 + quad * 4 + r;
            S[n][r] = (s_abs > q_abs) ? -1e30f : z[r];
          }
        } else {
#pragma unroll
          for (int r = 0; r < 4; ++r) S[n][r] = z[r];
        }
      } else {
#pragma unroll
        for (int r = 0; r < 4; ++r) S[n][r] = -1e30f;
      }
    }

    // online softmax (base-2); row r lives in the 16 lanes of this quad
    float alpha[4];
#pragma unroll
    for (int r = 0; r < 4; ++r) {
      float mx = S[0][r];
#pragma unroll
      for (int n = 1; n < 8; ++n) mx = fmaxf(mx, S[n][r]);
      mx = fmaxf(mx, __shfl_xor(mx, 1));
      mx = fmaxf(mx, __shfl_xor(mx, 2));
      mx = fmaxf(mx, __shfl_xor(mx, 4));
      mx = fmaxf(mx, __shfl_xor(mx, 8));
      float mnew = fmaxf(mrow[r], mx);
      alpha[r] = __builtin_amdgcn_exp2f(mrow[r] - mnew);
      mrow[r] = mnew;
    }
    float rs[4] = {0.f, 0.f, 0.f, 0.f};
#pragma unroll
    for (int n = 0; n < 8; ++n) {
#pragma unroll
      for (int r = 0; r < 4; ++r) {
        float p = __builtin_amdgcn_exp2f(S[n][r] - mrow[r]);  // masked -> 0
        rs[r] += p;
        Pw[(n >> 1) * 512 + ((quad * 4 + r) + ((n & 1) * 2 + (l15 >> 3)) * 16) * 8 + (l15 & 7)] = f2bf(p);
      }
    }
#pragma unroll
    for (int r = 0; r < 4; ++r) {
      float s = rs[r];
      s += __shfl_xor(s, 1);
      s += __shfl_xor(s, 2);
      s += __shfl_xor(s, 4);
      s += __shfl_xor(s, 8);
      lrow[r] = lrow[r] * alpha[r] + s;
#pragma unroll
      for (int n = 0; n < 4; ++n) Oacc[n][r] *= alpha[r];
    }
    // P strip is wave-private: drain DS writes before re-reading (no barrier)
    asm volatile("s_waitcnt lgkmcnt(0)" ::: "memory");

    // O += P V over the live 32-s blocks
    const int kblks = (nuse + 1) >> 1;
    for (int sb = 0; sb < kblks; ++sb) {
      s16x8 pf = *(const s16x8*)(Pw + sb * 512 + lane * 8);
#pragma unroll
      for (int n2 = 0; n2 < 4; ++n2) {
        s16x8 vfv = *(const s16x8*)(Vf + ((cb * 4 + sb) * 4 + n2) * 512 + lane * 8);
        Oacc[n2] = __builtin_amdgcn_mfma_f32_16x16x32_bf16(pf, vfv, Oacc[n2], 0, 0, 0);
      }
    }
  }

  float inv[4];
#pragma unroll
  for (int r = 0; r < 4; ++r) inv[r] = 1.0f / lrow[r];
  float* ob = out + ((long)b * 256 + q0 + quad * 4) * 64;
#pragma unroll
  for (int n = 0; n < 4; ++n)
#pragma unroll
    for (int r = 0; r < 4; ++r)
      ob[r * 64 + n * 16 + l15] = Oacc[n][r] * inv[r];
}

extern "C" void kernel_launch(void* const* d_in, const int* in_sizes, int n_in,
                              void* d_out, int out_size, void* d_ws, size_t ws_size,
                              hipStream_t stream) {
  const float* x = (const float*)d_in[0];
  const float* Wk = (const float*)d_in[1];
  const float* Wq = (const float*)d_in[2];
  const float* Wv = (const float*)d_in[3];
  float* out = (float*)d_out;
  short* Wt3 = (short*)d_ws;  // 147456 B

  prep_w<<<288, 256, 0, stream>>>(Wk, Wq, Wv, Wt3);
  fused_head<<<512, 1024, 0, stream>>>(x, Wt3, out);
}